// Round 1
// baseline (379.982 us; speedup 1.0000x reference)
//
#include <hip/hip_runtime.h>

typedef __attribute__((ext_vector_type(8))) short bfrag;   // 8 bf16 (4 VGPRs) MFMA operand
typedef __attribute__((ext_vector_type(4))) float f4;      // MFMA accumulator
typedef unsigned short u16;

#define LOG2E 1.4426950408889634f

__device__ inline u16 f2bf(float x) {
    unsigned u = __builtin_bit_cast(unsigned, x);
    u += 0x7FFFu + ((u >> 16) & 1u);   // round-to-nearest-even
    return (u16)(u >> 16);
}

// ---------------- cast fp32 -> bf16 (grid-stride) ----------------
__global__ void cast_bf16(const float* __restrict__ src, u16* __restrict__ dst, int n) {
    int i = blockIdx.x * blockDim.x + threadIdx.x;
    int stride = gridDim.x * blockDim.x;
    for (; i < n; i += stride) dst[i] = f2bf(src[i]);
}

// ---------------- concat biases [bq(2048) | bk(512) | bv(512)] ----------------
__global__ void bias_concat(const float* __restrict__ bq, const float* __restrict__ bk,
                            const float* __restrict__ bv, float* __restrict__ dst) {
    int i = blockIdx.x * 256 + threadIdx.x;
    if (i < 2048)      dst[i] = bq[i];
    else if (i < 2560) dst[i] = bk[i - 2048];
    else if (i < 3072) dst[i] = bv[i - 2560];
}

// ---------------- GEMM: C[M][N] = A[M][K](bf16) * B[N][K]^T(bf16) + bias ----------------
// 128x128 tile, BK=32, 256 threads = 4 waves (2x2), each wave 64x64 via 4x4 16x16x32 MFMA.
// LDS rows padded 32->40 shorts (80B stride) so ds_read_b128 is 2-way conflict (free).
__global__ __launch_bounds__(256) void gemm_bt(const u16* __restrict__ A, const u16* __restrict__ B,
                                               const float* __restrict__ bias, float* __restrict__ C,
                                               int M, int N, int K) {
    __shared__ u16 As[128 * 40];
    __shared__ u16 Bs[128 * 40];
    const int tm = blockIdx.y, tn = blockIdx.x;
    const int tid = threadIdx.x;
    const int w = tid >> 6, lane = tid & 63, quad = lane >> 4, l16 = lane & 15;
    const int wm = w >> 1, wn = w & 1;

    f4 acc[4][4];
#pragma unroll
    for (int i = 0; i < 4; i++)
#pragma unroll
        for (int j = 0; j < 4; j++) acc[i][j] = f4{0.f, 0.f, 0.f, 0.f};

    const int srow = tid >> 1, sk = (tid & 1) * 16;
    const u16* aSrc = A + (size_t)(tm * 128 + srow) * K + sk;
    const u16* bSrc = B + (size_t)(tn * 128 + srow) * K + sk;
    u16* aDst = &As[srow * 40 + sk];
    u16* bDst = &Bs[srow * 40 + sk];

    for (int k0 = 0; k0 < K; k0 += 32) {
        __syncthreads();
        *(bfrag*)aDst       = *(const bfrag*)aSrc;
        *(bfrag*)(aDst + 8) = *(const bfrag*)(aSrc + 8);
        *(bfrag*)bDst       = *(const bfrag*)bSrc;
        *(bfrag*)(bDst + 8) = *(const bfrag*)(bSrc + 8);
        aSrc += 32; bSrc += 32;
        __syncthreads();

        bfrag af[4], bf[4];
#pragma unroll
        for (int i = 0; i < 4; i++)
            af[i] = *(const bfrag*)(&As[(wm * 64 + i * 16 + l16) * 40 + quad * 8]);
#pragma unroll
        for (int j = 0; j < 4; j++)
            bf[j] = *(const bfrag*)(&Bs[(wn * 64 + j * 16 + l16) * 40 + quad * 8]);
#pragma unroll
        for (int i = 0; i < 4; i++)
#pragma unroll
            for (int j = 0; j < 4; j++)
                acc[i][j] = __builtin_amdgcn_mfma_f32_16x16x32_bf16(af[i], bf[j], acc[i][j], 0, 0, 0);
    }

#pragma unroll
    for (int i = 0; i < 4; i++) {
#pragma unroll
        for (int j = 0; j < 4; j++) {
            const int col = tn * 128 + wn * 64 + j * 16 + l16;
            const float bv = bias ? bias[col] : 0.f;
#pragma unroll
            for (int r = 0; r < 4; r++) {
                const int row = tm * 128 + wm * 64 + i * 16 + quad * 4 + r;
                C[(size_t)row * N + col] = acc[i][j][r] + bv;
            }
        }
    }
}

// ---------------- RoPE + repack to head-major bf16 ----------------
// QKV fp32 [2048][3072]  ->  Qr[16][2048][128], Kr[4][2048][128] (both roped), Vr[4][2048][128]
__global__ __launch_bounds__(256) void rope_repack(const float* __restrict__ QKV,
                                                   u16* __restrict__ Qr, u16* __restrict__ Kr,
                                                   u16* __restrict__ Vr) {
    const int s = blockIdx.x;
    const int t = threadIdx.x;
    const float* row = QKV + (size_t)s * 3072;
    const float fs = (float)s;

    // Q: 16 heads * 64 rotation pairs = 1024 pairs
    for (int p = t; p < 1024; p += 256) {
        const int hd = p >> 6, i = p & 63;
        const float inv = powf(10000.0f, -(float)i / 64.0f);
        float sn, cs;
        sincosf(fs * inv, &sn, &cs);
        const float q0 = row[hd * 128 + i];
        const float q1 = row[hd * 128 + i + 64];
        u16* qb = Qr + ((size_t)hd * 2048 + s) * 128;
        qb[i]      = f2bf(q0 * cs - q1 * sn);
        qb[i + 64] = f2bf(q1 * cs + q0 * sn);
    }
    // K: 4 heads * 64 pairs = 256 pairs
    {
        const int hd = t >> 6, i = t & 63;
        const float inv = powf(10000.0f, -(float)i / 64.0f);
        float sn, cs;
        sincosf(fs * inv, &sn, &cs);
        const float k0 = row[2048 + hd * 128 + i];
        const float k1 = row[2048 + hd * 128 + i + 64];
        u16* kb = Kr + ((size_t)hd * 2048 + s) * 128;
        kb[i]      = f2bf(k0 * cs - k1 * sn);
        kb[i + 64] = f2bf(k1 * cs + k0 * sn);
    }
    // V: 512 elements
    for (int e = t; e < 512; e += 256) {
        Vr[((size_t)(e >> 7) * 2048 + s) * 128 + (e & 127)] = f2bf(row[2560 + e]);
    }
}

// ---------------- flash attention (causal), bf16 MFMA ----------------
// grid (16 heads, 32 q-tiles of 64 rows). 256 threads = 4 waves, wave w owns rows w*16..w*16+15.
// Per 64-key tile: QK^T = 4 nt * 4 kb MFMA; PV = 8 ct * 2 kb MFMA.
__global__ __launch_bounds__(256) void flash_attn(const u16* __restrict__ Qr, const u16* __restrict__ Kr,
                                                  const u16* __restrict__ Vr, u16* __restrict__ attnout) {
    const int h = blockIdx.x;
    const int qt = blockIdx.y;
    const int kv = h >> 2;            // n_rep = 4
    const int tid = threadIdx.x;
    const int w = tid >> 6, lane = tid & 63, quad = lane >> 4, l16 = lane & 15;

    __shared__ u16 ks[64 * 136];      // K tile [64 keys][128] padded
    __shared__ u16 vsh[128 * 72];     // V tile transposed [128 cols][64 keys] padded
    __shared__ u16 ps[4][16 * 72];    // per-wave P tile [16 rows][64 keys] padded

    // Q fragments for this wave's 16 rows (A-operand layout)
    bfrag aq[4];
    const u16* qbase = Qr + ((size_t)(h * 2048 + qt * 64 + w * 16 + l16)) * 128 + quad * 8;
#pragma unroll
    for (int kb = 0; kb < 4; kb++) aq[kb] = *(const bfrag*)(qbase + kb * 32);

    f4 oacc[8];
#pragma unroll
    for (int ct = 0; ct < 8; ct++) oacc[ct] = f4{0.f, 0.f, 0.f, 0.f};
    float m_i[4] = {-INFINITY, -INFINITY, -INFINITY, -INFINITY};
    float l_i[4] = {0.f, 0.f, 0.f, 0.f};

    const int rowbase = qt * 64 + w * 16 + quad * 4;

    for (int kt = 0; kt <= qt; kt++) {
        __syncthreads();
        {   // stage K tile: thread t copies 32 elems (row t/4, cols (t&3)*32..+32)
            const int r = tid >> 2, c0 = (tid & 3) * 32;
            const u16* src = Kr + ((size_t)(kv * 2048 + kt * 64 + r)) * 128 + c0;
            u16* dst = &ks[r * 136 + c0];
#pragma unroll
            for (int u = 0; u < 4; u++) *(bfrag*)(dst + u * 8) = *(const bfrag*)(src + u * 8);
        }
        {   // stage V transposed
            const int r = tid >> 2, c0 = (tid & 3) * 32;
            const u16* src = Vr + ((size_t)(kv * 2048 + kt * 64 + r)) * 128 + c0;
            bfrag tmp[4];
#pragma unroll
            for (int u = 0; u < 4; u++) tmp[u] = *(const bfrag*)(src + u * 8);
#pragma unroll
            for (int u = 0; u < 4; u++)
#pragma unroll
                for (int j = 0; j < 8; j++) vsh[(c0 + u * 8 + j) * 72 + r] = (u16)tmp[u][j];
        }
        __syncthreads();

        // scores: 16 x 64 per wave
        f4 sc[4];
#pragma unroll
        for (int nt = 0; nt < 4; nt++) {
            f4 c = f4{0.f, 0.f, 0.f, 0.f};
            const u16* kb_base = &ks[(nt * 16 + l16) * 136 + quad * 8];
#pragma unroll
            for (int kb = 0; kb < 4; kb++) {
                bfrag b = *(const bfrag*)(kb_base + kb * 32);
                c = __builtin_amdgcn_mfma_f32_16x16x32_bf16(aq[kb], b, c, 0, 0, 0);
            }
            sc[nt] = c * 0.08838834764831845f;   // 1/sqrt(128)
        }

        // causal mask
#pragma unroll
        for (int nt = 0; nt < 4; nt++) {
            const int col = kt * 64 + nt * 16 + l16;
#pragma unroll
            for (int r = 0; r < 4; r++)
                if (col > rowbase + r) sc[nt][r] = -INFINITY;
        }

        // online softmax (row stats live per (quad, r); reduce over the 16 lanes of the quad)
        float alpha[4];
#pragma unroll
        for (int r = 0; r < 4; r++) {
            float mx = fmaxf(fmaxf(sc[0][r], sc[1][r]), fmaxf(sc[2][r], sc[3][r]));
#pragma unroll
            for (int off = 1; off < 16; off <<= 1) mx = fmaxf(mx, __shfl_xor(mx, off, 64));
            const float mn = fmaxf(m_i[r], mx);
            alpha[r] = exp2f((m_i[r] - mn) * LOG2E);
            m_i[r] = mn;
            float sum = 0.f;
#pragma unroll
            for (int nt = 0; nt < 4; nt++) {
                const float p = exp2f((sc[nt][r] - mn) * LOG2E);
                sc[nt][r] = p;
                sum += p;
            }
#pragma unroll
            for (int off = 1; off < 16; off <<= 1) sum += __shfl_xor(sum, off, 64);
            l_i[r] = l_i[r] * alpha[r] + sum;
        }

        // P (C-layout) -> LDS -> A-layout; rescale O
#pragma unroll
        for (int nt = 0; nt < 4; nt++)
#pragma unroll
            for (int r = 0; r < 4; r++)
                ps[w][(quad * 4 + r) * 72 + nt * 16 + l16] = f2bf(sc[nt][r]);
#pragma unroll
        for (int ct = 0; ct < 8; ct++)
#pragma unroll
            for (int r = 0; r < 4; r++) oacc[ct][r] *= alpha[r];

        bfrag pa[2];
#pragma unroll
        for (int kb2 = 0; kb2 < 2; kb2++)
            pa[kb2] = *(const bfrag*)(&ps[w][l16 * 72 + kb2 * 32 + quad * 8]);

        // O += P * V
#pragma unroll
        for (int ct = 0; ct < 8; ct++) {
            const u16* vb = &vsh[(ct * 16 + l16) * 72 + quad * 8];
#pragma unroll
            for (int kb2 = 0; kb2 < 2; kb2++) {
                bfrag b = *(const bfrag*)(vb + kb2 * 32);
                oacc[ct] = __builtin_amdgcn_mfma_f32_16x16x32_bf16(pa[kb2], b, oacc[ct], 0, 0, 0);
            }
        }
    }

    // epilogue: normalize, write bf16 attn_out in [S][nH*128] layout
    float inv_l[4];
#pragma unroll
    for (int r = 0; r < 4; r++) inv_l[r] = 1.0f / l_i[r];
#pragma unroll
    for (int ct = 0; ct < 8; ct++) {
        const int col = h * 128 + ct * 16 + l16;
#pragma unroll
        for (int r = 0; r < 4; r++)
            attnout[(size_t)(rowbase + r) * 2048 + col] = f2bf(oacc[ct][r] * inv_l[r]);
    }
}

// ---------------- launch ----------------
extern "C" void kernel_launch(void* const* d_in, const int* in_sizes, int n_in,
                              void* d_out, int out_size, void* d_ws, size_t ws_size,
                              hipStream_t stream) {
    const float* X  = (const float*)d_in[0];
    // d_in[1] = attention_mask (causal, implemented analytically), d_in[2] = position_ids (== arange)
    const float* wq = (const float*)d_in[3];
    const float* bq = (const float*)d_in[4];
    const float* wk = (const float*)d_in[5];
    const float* bk = (const float*)d_in[6];
    const float* wv = (const float*)d_in[7];
    const float* bv = (const float*)d_in[8];
    const float* wo = (const float*)d_in[9];

    char* ws = (char*)d_ws;
    u16*   Xb      = (u16*)(ws);                         // 8 MB
    u16*   Wqkv    = (u16*)(ws + 8388608);               // 12 MB  [3072][2048]
    u16*   Wo      = (u16*)(ws + 20971520);              // 8 MB
    float* biasqkv = (float*)(ws + 29360128);            // 12 KB
    float* QKV     = (float*)(ws + 29372416);            // 24 MB  [2048][3072]
    u16*   Qr      = (u16*)(ws + 54538240);              // 8 MB   [16][2048][128]
    u16*   Kr      = (u16*)(ws + 62926848);              // 2 MB   [4][2048][128]
    u16*   Vr      = (u16*)(ws + 65024000);              // 2 MB
    u16*   attnout = (u16*)(ws + 67121152);              // 8 MB   [2048][2048]

    cast_bf16<<<4096, 256, 0, stream>>>(X,  Xb,                2048 * 2048);
    cast_bf16<<<4096, 256, 0, stream>>>(wq, Wqkv,              2048 * 2048);
    cast_bf16<<<1024, 256, 0, stream>>>(wk, Wqkv + 2048 * 2048, 512 * 2048);
    cast_bf16<<<1024, 256, 0, stream>>>(wv, Wqkv + 2560 * 2048, 512 * 2048);
    cast_bf16<<<4096, 256, 0, stream>>>(wo, Wo,                2048 * 2048);
    bias_concat<<<12, 256, 0, stream>>>(bq, bk, bv, biasqkv);

    gemm_bt<<<dim3(24, 16), 256, 0, stream>>>(Xb, Wqkv, biasqkv, QKV, 2048, 3072, 2048);
    rope_repack<<<2048, 256, 0, stream>>>(QKV, Qr, Kr, Vr);
    flash_attn<<<dim3(16, 32), 256, 0, stream>>>(Qr, Kr, Vr, attnout);
    gemm_bt<<<dim3(16, 16), 256, 0, stream>>>(attnout, Wo, nullptr, (float*)d_out, 2048, 2048, 2048);
}

// Round 2
// 343.001 us; speedup vs baseline: 1.1078x; 1.1078x over previous
//
#include <hip/hip_runtime.h>

typedef __attribute__((ext_vector_type(8))) short bfrag;   // 8 bf16 (4 VGPRs) MFMA operand
typedef __attribute__((ext_vector_type(4))) float f4;      // MFMA accumulator
typedef unsigned short u16;

#define LOG2E 1.4426950408889634f

__device__ inline u16 f2bf(float x) {
    unsigned u = __builtin_bit_cast(unsigned, x);
    u += 0x7FFFu + ((u >> 16) & 1u);   // round-to-nearest-even
    return (u16)(u >> 16);
}

__device__ inline void gload16(const u16* g, u16* l) {
    // async global->LDS, 16B/lane; LDS dst = wave-uniform base + lane*16
    __builtin_amdgcn_global_load_lds((const __attribute__((address_space(1))) u16*)g,
                                     (__attribute__((address_space(3))) u16*)l, 16, 0, 0);
}

// ---------------- cast fp32 -> bf16 (grid-stride) ----------------
__global__ void cast_bf16(const float* __restrict__ src, u16* __restrict__ dst, int n) {
    int i = blockIdx.x * blockDim.x + threadIdx.x;
    int stride = gridDim.x * blockDim.x;
    for (; i < n; i += stride) dst[i] = f2bf(src[i]);
}

// ---------------- concat biases [bq(2048) | bk(512) | bv(512)] ----------------
__global__ void bias_concat(const float* __restrict__ bq, const float* __restrict__ bk,
                            const float* __restrict__ bv, float* __restrict__ dst) {
    int i = blockIdx.x * 256 + threadIdx.x;
    if (i < 2048)      dst[i] = bq[i];
    else if (i < 2560) dst[i] = bk[i - 2048];
    else if (i < 3072) dst[i] = bv[i - 2560];
}

// ---------------- GEMM: C[M][N] = A[M][K](bf16) * B[N][K]^T(bf16) + bias ----------------
// 128x128 tile, BK=32, 256 threads = 4 waves (2x2), each wave 64x64 via 4x4 16x16x32 MFMA.
// Staging via global_load_lds width=16 into unpadded [128][32] LDS (m97 structure).
__global__ __launch_bounds__(256) void gemm_bt(const u16* __restrict__ A, const u16* __restrict__ B,
                                               const float* __restrict__ bias, float* __restrict__ C,
                                               int M, int N, int K) {
    __shared__ u16 As[128 * 32];
    __shared__ u16 Bs[128 * 32];
    const int tm = blockIdx.y, tn = blockIdx.x;
    const int tid = threadIdx.x;
    const int w = tid >> 6, lane = tid & 63, quad = lane >> 4, l16 = lane & 15;
    const int wm = w >> 1, wn = w & 1;

    f4 acc[4][4];
#pragma unroll
    for (int i = 0; i < 4; i++)
#pragma unroll
        for (int j = 0; j < 4; j++) acc[i][j] = f4{0.f, 0.f, 0.f, 0.f};

    // wave w stages rows [w*32, w*32+32) of A and B; lane L covers row L/4, col-block (L&3)*8
    const int srow = w * 32 + (lane >> 2);
    const int scol = (lane & 3) * 8;
    const u16* aPtr = A + (size_t)(tm * 128 + srow) * K + scol;
    const u16* bPtr = B + (size_t)(tn * 128 + srow) * K + scol;
    u16* aLds0 = &As[(w * 32) * 32];
    u16* aLds1 = &As[(w * 32 + 16) * 32];
    u16* bLds0 = &Bs[(w * 32) * 32];
    u16* bLds1 = &Bs[(w * 32 + 16) * 32];
    const size_t rowskip = (size_t)16 * K;

    for (int k0 = 0; k0 < K; k0 += 32) {
        __syncthreads();
        gload16(aPtr,           aLds0);
        gload16(aPtr + rowskip, aLds1);
        gload16(bPtr,           bLds0);
        gload16(bPtr + rowskip, bLds1);
        aPtr += 32; bPtr += 32;
        __syncthreads();

        bfrag af[4], bf[4];
#pragma unroll
        for (int i = 0; i < 4; i++)
            af[i] = *(const bfrag*)(&As[(wm * 64 + i * 16 + l16) * 32 + quad * 8]);
#pragma unroll
        for (int j = 0; j < 4; j++)
            bf[j] = *(const bfrag*)(&Bs[(wn * 64 + j * 16 + l16) * 32 + quad * 8]);
#pragma unroll
        for (int i = 0; i < 4; i++)
#pragma unroll
            for (int j = 0; j < 4; j++)
                acc[i][j] = __builtin_amdgcn_mfma_f32_16x16x32_bf16(af[i], bf[j], acc[i][j], 0, 0, 0);
    }

#pragma unroll
    for (int i = 0; i < 4; i++) {
#pragma unroll
        for (int j = 0; j < 4; j++) {
            const int col = tn * 128 + wn * 64 + j * 16 + l16;
            const float bv = bias ? bias[col] : 0.f;
#pragma unroll
            for (int r = 0; r < 4; r++) {
                const int row = tm * 128 + wm * 64 + i * 16 + quad * 4 + r;
                C[(size_t)row * N + col] = acc[i][j][r] + bv;
            }
        }
    }
}

// ---------------- RoPE + repack to head-major bf16 ----------------
// QKV fp32 [2048][3072] -> Qr[16][2048][128], Kr[4][2048][128] (roped), Vr[4][2048][128]
__global__ __launch_bounds__(256) void rope_repack(const float* __restrict__ QKV,
                                                   u16* __restrict__ Qr, u16* __restrict__ Kr,
                                                   u16* __restrict__ Vr) {
    const int s = blockIdx.x;
    const int t = threadIdx.x;
    const float* row = QKV + (size_t)s * 3072;
    const float fs = (float)s;

    for (int p = t; p < 1024; p += 256) {
        const int hd = p >> 6, i = p & 63;
        const float inv = powf(10000.0f, -(float)i / 64.0f);
        float sn, cs;
        sincosf(fs * inv, &sn, &cs);
        const float q0 = row[hd * 128 + i];
        const float q1 = row[hd * 128 + i + 64];
        u16* qb = Qr + ((size_t)hd * 2048 + s) * 128;
        qb[i]      = f2bf(q0 * cs - q1 * sn);
        qb[i + 64] = f2bf(q1 * cs + q0 * sn);
    }
    {
        const int hd = t >> 6, i = t & 63;
        const float inv = powf(10000.0f, -(float)i / 64.0f);
        float sn, cs;
        sincosf(fs * inv, &sn, &cs);
        const float k0 = row[2048 + hd * 128 + i];
        const float k1 = row[2048 + hd * 128 + i + 64];
        u16* kb = Kr + ((size_t)hd * 2048 + s) * 128;
        kb[i]      = f2bf(k0 * cs - k1 * sn);
        kb[i + 64] = f2bf(k1 * cs + k0 * sn);
    }
    for (int e = t; e < 512; e += 256) {
        Vr[((size_t)(e >> 7) * 2048 + s) * 128 + (e & 127)] = f2bf(row[2560 + e]);
    }
}

// ---------------- V transpose: Vr[4][2048][128] -> Vt[4][128][2048] ----------------
__global__ __launch_bounds__(256) void transpose_v(const u16* __restrict__ Vr, u16* __restrict__ Vt) {
    __shared__ u16 tile[64 * 72];
    const int d0 = blockIdx.x * 64, s0 = blockIdx.y * 64, kv = blockIdx.z;
    const int t = threadIdx.x;
#pragma unroll
    for (int p = 0; p < 2; p++) {
        const int sr = p * 32 + (t >> 3), dc = (t & 7) * 8;
        *(bfrag*)&tile[sr * 72 + dc] =
            *(const bfrag*)&Vr[((size_t)(kv * 2048 + s0 + sr)) * 128 + d0 + dc];
    }
    __syncthreads();
#pragma unroll
    for (int p = 0; p < 2; p++) {
        const int dr = p * 32 + (t >> 3), sc = (t & 7) * 8;
        bfrag v;
#pragma unroll
        for (int j = 0; j < 8; j++) v[j] = (short)tile[(sc + j) * 72 + dr];
        *(bfrag*)&Vt[((size_t)(kv * 128 + d0 + dr)) * 2048 + s0 + sc] = v;
    }
}

// ---------------- flash attention (causal), bf16 MFMA, diagonal-paired ----------------
// grid (16 heads, 32 pair-blocks), 128 threads = 2 waves of 16 q-rows.
// Block pb handles 32-row groups g=pb and g=63-pb -> uniform 33 key-tiles per block.
__global__ __launch_bounds__(128) void flash_attn(const u16* __restrict__ Qr, const u16* __restrict__ Kr,
                                                  const u16* __restrict__ Vt, u16* __restrict__ attnout) {
    const int h = blockIdx.x;
    const int pb = blockIdx.y;
    const int kv = h >> 2;            // n_rep = 4
    const int tid = threadIdx.x;
    const int w = tid >> 6, lane = tid & 63, quad = lane >> 4, l16 = lane & 15;

    __shared__ u16 ks[64 * 136];      // K tile [64 keys][128 d]
    __shared__ u16 vt[128 * 72];      // V^T tile [128 d][64 keys]
    __shared__ u16 ps[2][16 * 72];    // per-wave P tile [16 rows][64 keys]

#pragma unroll
    for (int seg = 0; seg < 2; seg++) {
        const int g = seg ? (63 - pb) : pb;
        const int rowbase = g * 32 + w * 16 + quad * 4;
        const int ktn = g / 2 + 1;    // key tiles needed (64-wide) for rows [g*32, g*32+32)

        bfrag aq[4];
        const u16* qbase = Qr + ((size_t)(h * 2048 + g * 32 + w * 16 + l16)) * 128 + quad * 8;
#pragma unroll
        for (int kb = 0; kb < 4; kb++) aq[kb] = *(const bfrag*)(qbase + kb * 32);

        f4 oacc[8];
#pragma unroll
        for (int ct = 0; ct < 8; ct++) oacc[ct] = f4{0.f, 0.f, 0.f, 0.f};
        float m_i[4] = {-INFINITY, -INFINITY, -INFINITY, -INFINITY};
        float l_i[4] = {0.f, 0.f, 0.f, 0.f};

        for (int kt = 0; kt < ktn; kt++) {
            __syncthreads();
            {   // stage K tile: 2 threads/row, 128B each
                const int r = tid >> 1, c0 = (tid & 1) * 64;
                const u16* src = Kr + ((size_t)(kv * 2048 + kt * 64 + r)) * 128 + c0;
                u16* dst = &ks[r * 136 + c0];
#pragma unroll
                for (int u = 0; u < 8; u++) *(bfrag*)(dst + u * 8) = *(const bfrag*)(src + u * 8);
            }
            {   // stage V^T tile: 1 thread/row (d), 64 keys = 128B
                const u16* src = Vt + ((size_t)(kv * 128 + tid)) * 2048 + kt * 64;
                u16* dst = &vt[tid * 72];
#pragma unroll
                for (int u = 0; u < 8; u++) *(bfrag*)(dst + u * 8) = *(const bfrag*)(src + u * 8);
            }
            __syncthreads();

            // scores: wave's 16 rows x 64 keys
            f4 sc[4];
#pragma unroll
            for (int nt = 0; nt < 4; nt++) {
                f4 c = f4{0.f, 0.f, 0.f, 0.f};
                const u16* kb_base = &ks[(nt * 16 + l16) * 136 + quad * 8];
#pragma unroll
                for (int kb = 0; kb < 4; kb++) {
                    bfrag b = *(const bfrag*)(kb_base + kb * 32);
                    c = __builtin_amdgcn_mfma_f32_16x16x32_bf16(aq[kb], b, c, 0, 0, 0);
                }
                sc[nt] = c * 0.08838834764831845f;   // 1/sqrt(128)
            }

            if (kt == ktn - 1) {  // only the diagonal tile needs masking
#pragma unroll
                for (int nt = 0; nt < 4; nt++) {
                    const int col = kt * 64 + nt * 16 + l16;
#pragma unroll
                    for (int r = 0; r < 4; r++)
                        if (col > rowbase + r) sc[nt][r] = -INFINITY;
                }
            }

            float alpha[4];
#pragma unroll
            for (int r = 0; r < 4; r++) {
                float mx = fmaxf(fmaxf(sc[0][r], sc[1][r]), fmaxf(sc[2][r], sc[3][r]));
#pragma unroll
                for (int off = 1; off < 16; off <<= 1) mx = fmaxf(mx, __shfl_xor(mx, off, 64));
                const float mn = fmaxf(m_i[r], mx);
                alpha[r] = exp2f((m_i[r] - mn) * LOG2E);
                m_i[r] = mn;
                float sum = 0.f;
#pragma unroll
                for (int nt = 0; nt < 4; nt++) {
                    const float p = exp2f((sc[nt][r] - mn) * LOG2E);
                    sc[nt][r] = p;
                    sum += p;
                }
#pragma unroll
                for (int off = 1; off < 16; off <<= 1) sum += __shfl_xor(sum, off, 64);
                l_i[r] = l_i[r] * alpha[r] + sum;
            }

            // P (C-layout) -> LDS -> A-layout; rescale O
#pragma unroll
            for (int nt = 0; nt < 4; nt++)
#pragma unroll
                for (int r = 0; r < 4; r++)
                    ps[w][(quad * 4 + r) * 72 + nt * 16 + l16] = f2bf(sc[nt][r]);
#pragma unroll
            for (int ct = 0; ct < 8; ct++)
#pragma unroll
                for (int r = 0; r < 4; r++) oacc[ct][r] *= alpha[r];

            bfrag pa[2];
#pragma unroll
            for (int kb2 = 0; kb2 < 2; kb2++)
                pa[kb2] = *(const bfrag*)(&ps[w][l16 * 72 + kb2 * 32 + quad * 8]);

#pragma unroll
            for (int ct = 0; ct < 8; ct++) {
                const u16* vb = &vt[(ct * 16 + l16) * 72 + quad * 8];
#pragma unroll
                for (int kb2 = 0; kb2 < 2; kb2++) {
                    bfrag b = *(const bfrag*)(vb + kb2 * 32);
                    oacc[ct] = __builtin_amdgcn_mfma_f32_16x16x32_bf16(pa[kb2], b, oacc[ct], 0, 0, 0);
                }
            }
        }

        // epilogue: normalize, write bf16 attn_out in [S][nH*128] layout
        float inv_l[4];
#pragma unroll
        for (int r = 0; r < 4; r++) inv_l[r] = 1.0f / l_i[r];
#pragma unroll
        for (int ct = 0; ct < 8; ct++) {
            const int col = h * 128 + ct * 16 + l16;
#pragma unroll
            for (int r = 0; r < 4; r++)
                attnout[(size_t)(rowbase + r) * 2048 + col] = f2bf(oacc[ct][r] * inv_l[r]);
        }
        __syncthreads();   // don't let seg1 staging race seg0's PV reads
    }
}

// ---------------- launch ----------------
extern "C" void kernel_launch(void* const* d_in, const int* in_sizes, int n_in,
                              void* d_out, int out_size, void* d_ws, size_t ws_size,
                              hipStream_t stream) {
    const float* X  = (const float*)d_in[0];
    const float* wq = (const float*)d_in[3];
    const float* bq = (const float*)d_in[4];
    const float* wk = (const float*)d_in[5];
    const float* bk = (const float*)d_in[6];
    const float* wv = (const float*)d_in[7];
    const float* bv = (const float*)d_in[8];
    const float* wo = (const float*)d_in[9];

    char* ws = (char*)d_ws;
    u16*   Xb      = (u16*)(ws);                         // 8 MB
    u16*   Wqkv    = (u16*)(ws + 8388608);               // 12 MB  [3072][2048]
    u16*   Wo      = (u16*)(ws + 20971520);              // 8 MB
    float* biasqkv = (float*)(ws + 29360128);            // 12 KB
    float* QKV     = (float*)(ws + 29372416);            // 24 MB  [2048][3072]
    u16*   Qr      = (u16*)(ws + 54538240);              // 8 MB   [16][2048][128]
    u16*   Kr      = (u16*)(ws + 62926848);              // 2 MB   [4][2048][128]
    u16*   Vr      = (u16*)(ws + 65024000);              // 2 MB   [4][2048][128]
    u16*   attnout = (u16*)(ws + 67121152);              // 8 MB   [2048][2048]
    u16*   Vt      = (u16*)(ws + 75509760);              // 2 MB   [4][128][2048]

    cast_bf16<<<4096, 256, 0, stream>>>(X,  Xb,                2048 * 2048);
    cast_bf16<<<4096, 256, 0, stream>>>(wq, Wqkv,              2048 * 2048);
    cast_bf16<<<1024, 256, 0, stream>>>(wk, Wqkv + 2048 * 2048, 512 * 2048);
    cast_bf16<<<1024, 256, 0, stream>>>(wv, Wqkv + 2560 * 2048, 512 * 2048);
    cast_bf16<<<4096, 256, 0, stream>>>(wo, Wo,                2048 * 2048);
    bias_concat<<<12, 256, 0, stream>>>(bq, bk, bv, biasqkv);

    gemm_bt<<<dim3(24, 16), 256, 0, stream>>>(Xb, Wqkv, biasqkv, QKV, 2048, 3072, 2048);
    rope_repack<<<2048, 256, 0, stream>>>(QKV, Qr, Kr, Vr);
    transpose_v<<<dim3(2, 32, 4), 256, 0, stream>>>(Vr, Vt);
    flash_attn<<<dim3(16, 32), 128, 0, stream>>>(Qr, Kr, Vt, attnout);
    gemm_bt<<<dim3(16, 16), 256, 0, stream>>>(attnout, Wo, nullptr, (float*)d_out, 2048, 2048, 2048);
}